// Round 2
// baseline (110.845 us; speedup 1.0000x reference)
//
#include <hip/hip_runtime.h>
#include <math.h>

#define T 8192
#define D 36
#define NCH 64
#define CHUNK (T / NCH)   // 128
#define RPT 4             // rows per thread in argmax

// ws layout (floats):
// [0,2T)    Qp  as float2[T] (q0,q1 per row)
// [2T,4T)   Kp  as float2[T]
// [4T,6T)   Qs  as float2[T]
// [6T,8T)   Ks  as float2[T]
// [8T,9T)   Vop   [9T,10T) Varg   [10T,11T) Vs
// [11T, 11T + 2*NCH*2T)  partials: float2[NCH][2T]  {bestval, as_float(bestidx)}
//                        indexed [c][head*T + row]  (transposed for coalescing)

__global__ __launch_bounds__(256) void proj_kernel(
    const float* __restrict__ E,
    const float* __restrict__ WQp, const float* __restrict__ WKp,
    const float* __restrict__ WVop, const float* __restrict__ WVarg,
    const float* __restrict__ WQs, const float* __restrict__ WKs,
    const float* __restrict__ WVs, float* __restrict__ ws) {
    int t = blockIdx.x * blockDim.x + threadIdx.x;
    if (t >= T) return;
    float e[D];
    const float4* Er = (const float4*)(E + t * D);   // 144B row stride, 16B aligned
#pragma unroll
    for (int i = 0; i < D / 4; ++i) {
        float4 v = Er[i];
        e[4 * i + 0] = v.x; e[4 * i + 1] = v.y;
        e[4 * i + 2] = v.z; e[4 * i + 3] = v.w;
    }
    float qp0 = 0.f, qp1 = 0.f, kp0 = 0.f, kp1 = 0.f;
    float qs0 = 0.f, qs1 = 0.f, ks0 = 0.f, ks1 = 0.f;
    float vop = 0.f, varg = 0.f, vs = 0.f;
#pragma unroll
    for (int d = 0; d < D; ++d) {
        float ed = e[d];
        qp0 = fmaf(ed, WQp[d], qp0);
        qp1 = fmaf(ed, WQp[D + d], qp1);
        kp0 = fmaf(ed, WKp[d], kp0);
        kp1 = fmaf(ed, WKp[D + d], kp1);
        qs0 = fmaf(ed, WQs[d], qs0);
        qs1 = fmaf(ed, WQs[D + d], qs1);
        ks0 = fmaf(ed, WKs[d], ks0);
        ks1 = fmaf(ed, WKs[D + d], ks1);
        vop  = fmaf(ed, WVop[d], vop);
        varg = fmaf(ed, WVarg[d], varg);
        vs   = fmaf(ed, WVs[d], vs);
    }
    float2* Qp = (float2*)ws;
    float2* Kp = (float2*)(ws + 2 * T);
    float2* Qs = (float2*)(ws + 4 * T);
    float2* Ks = (float2*)(ws + 6 * T);
    Qp[t] = make_float2(qp0, qp1);
    Kp[t] = make_float2(kp0, kp1);
    Qs[t] = make_float2(qs0, qs1);
    Ks[t] = make_float2(ks0, ks1);
    ws[8 * T + t]  = vop;
    ws[9 * T + t]  = varg;
    ws[10 * T + t] = vs;
}

// grid: (T/(256*RPT) = 8 row-blocks, NCH=64 chunks, 2 heads), block 256
__global__ __launch_bounds__(256) void argmax_kernel(
    const float* __restrict__ wsf, float2* __restrict__ part) {
    const int head = blockIdx.z;
    const float2* Q = (const float2*)(wsf + head * 4 * T);
    const float2* K = (const float2*)(wsf + 2 * T + head * 4 * T);

    __shared__ float2 sk[CHUNK];
    const int c  = blockIdx.y;
    const int j0 = c * CHUNK;
    if (threadIdx.x < CHUNK) sk[threadIdx.x] = K[j0 + threadIdx.x];
    __syncthreads();

    const int rbase = blockIdx.x * (256 * RPT) + threadIdx.x;
    float2 q[RPT];
    float best[RPT];
    int   bi[RPT];
#pragma unroll
    for (int i = 0; i < RPT; ++i) {
        q[i] = Q[rbase + 256 * i];
        best[i] = -INFINITY;
        bi[i] = 0;
    }
#pragma unroll 8
    for (int k = 0; k < CHUNK; ++k) {
        float2 kk = sk[k];
#pragma unroll
        for (int i = 0; i < RPT; ++i) {
            float s = fmaf(q[i].x, kk.x, q[i].y * kk.y);
            bool gt = s > best[i];        // strict > keeps first occurrence
            best[i] = gt ? s : best[i];
            bi[i]   = gt ? k : bi[i];
        }
    }
#pragma unroll
    for (int i = 0; i < RPT; ++i) {
        const int prow = head * T + rbase + 256 * i;
        part[c * (2 * T) + prow] = make_float2(best[i], __int_as_float(j0 + bi[i]));
    }
}

__global__ __launch_bounds__(256) void finalize_kernel(
    const float* __restrict__ wsf, const float2* __restrict__ part,
    float* __restrict__ out) {
    int idx = blockIdx.x * blockDim.x + threadIdx.x;  // 0 .. 2T-1
    if (idx >= 2 * T) return;
    float best = -INFINITY;
    int bj = 0;
#pragma unroll
    for (int c = 0; c < NCH; ++c) {   // ascending chunk order => first occurrence
        float2 p = part[c * (2 * T) + idx];
        bool gt = p.x > best;
        best = gt ? p.x : best;
        bj   = gt ? __float_as_int(p.y) : bj;
    }
    const int head = idx >> 13;
    const int row  = idx & (T - 1);
    const float* Vop  = wsf + 8 * T;
    const float* Varg = wsf + 9 * T;
    const float* Vs   = wsf + 10 * T;
    if (head == 0) {
        out[row]     = Vop[bj];
        out[T + row] = Varg[bj];
    } else {
        out[2 * T + row] = Vs[bj];
    }
}

extern "C" void kernel_launch(void* const* d_in, const int* in_sizes, int n_in,
                              void* d_out, int out_size, void* d_ws, size_t ws_size,
                              hipStream_t stream) {
    const float* E     = (const float*)d_in[0];
    const float* WQp   = (const float*)d_in[1];
    const float* WKp   = (const float*)d_in[2];
    const float* WVop  = (const float*)d_in[3];
    const float* WVarg = (const float*)d_in[4];
    const float* WQs   = (const float*)d_in[5];
    const float* WKs   = (const float*)d_in[6];
    const float* WVs   = (const float*)d_in[7];
    float* out = (float*)d_out;

    float* wsf = (float*)d_ws;
    float2* part = (float2*)(wsf + 11 * T);

    proj_kernel<<<T / 256, 256, 0, stream>>>(E, WQp, WKp, WVop, WVarg, WQs, WKs, WVs, wsf);

    dim3 gB(T / (256 * RPT), NCH, 2);
    argmax_kernel<<<gB, 256, 0, stream>>>(wsf, part);

    finalize_kernel<<<(2 * T) / 256, 256, 0, stream>>>(wsf, part, out);
}